// Round 16
// baseline (771.107 us; speedup 1.0000x reference)
//
#include <hip/hip_runtime.h>
#include <math.h>

// R15 = R14 (763us, 16 waves/CU) + spill kill:
//  - amdgpu_waves_per_eu(4,4): LDS caps us at 4 waves/EU anyway; tell the
//    allocator so its budget is 128 VGPR, not 64 (R14: VGPR=64 + 15.7MB
//    scratch WRITE_SIZE).
//  - Persistent state out of registers: pe -> fp32 LDS table (stride 68,
//    2-way max aliasing), wic -> per-iter float4 load from w_in (L1),
//    wo4 -> per-iter loads in head. Frees ~36 always-live VGPRs.
// LDS = 24576 g2 + 16x7296 slots + 4352 peL = 145664 (1 block/CU, 16 waves).

typedef __attribute__((ext_vector_type(8))) short s8v;
typedef __attribute__((ext_vector_type(4))) short s4v;
typedef __attribute__((ext_vector_type(4))) float f4v;
typedef __attribute__((ext_vector_type(4))) unsigned int u4v;

#define MFMA32(A, B, C) __builtin_amdgcn_mfma_f32_16x16x32_bf16((A), (B), (C), 0, 0, 0)
#define MFMA16(A, B, C) __builtin_amdgcn_mfma_f32_16x16x16bf16_1k((A), (B), (C), 0, 0, 0)

static __device__ __forceinline__ unsigned short f2b(float f) {
  return __builtin_bit_cast(unsigned short, (__bf16)f);
}
static __device__ __forceinline__ float b2f(unsigned short h) {
  return __builtin_bit_cast(float, ((unsigned)h) << 16);
}

// ---- prologue: pack weights into MFMA B-fragment order (bf16) ----
// tile t: lane l holds B[k = kk*32 + (l>>4)*8 + e][n = j*16 + (l&15)], e=0..7
// bases: qkv l*24 + kk*12 + j | ow 48 + l*8 + kk*4 + j
//        ff1 64 + l*32 + kk*16 + j | ff2 128 + l*32 + kkg*4 + j
__global__ __launch_bounds__(256) void wpack(
    const float* __restrict__ qkv_w, const float* __restrict__ ow,
    const float* __restrict__ ff1_w, const float* __restrict__ ff2_w,
    unsigned int* __restrict__ ws) {
  int gid = blockIdx.x * 256 + threadIdx.x;   // 0..12287
  int tIdx = gid >> 6, lane = gid & 63;
  int ln = lane & 15, grp = lane >> 4;
  const float* src;
  if (tIdx < 48) {
    int l = tIdx / 24, r = tIdx % 24, kk = r / 12, j = r % 12;
    src = qkv_w + l * 12288 + (j * 16 + ln) * 64 + kk * 32 + grp * 8;
  } else if (tIdx < 64) {
    int u = tIdx - 48, l = u / 8, r = u % 8, kk = r / 4, j = r % 4;
    src = ow + l * 4096 + (j * 16 + ln) * 64 + kk * 32 + grp * 8;
  } else if (tIdx < 128) {
    int u = tIdx - 64, l = u / 32, r = u % 32, kk = r / 16, j = r % 16;
    src = ff1_w + l * 16384 + (j * 16 + ln) * 64 + kk * 32 + grp * 8;
  } else {
    int u = tIdx - 128, l = u / 32, r = u % 32, kk = r / 4, j = r % 4;
    src = ff2_w + l * 16384 + (j * 16 + ln) * 256 + kk * 32 + grp * 8;
  }
  unsigned p[4];
#pragma unroll
  for (int e = 0; e < 4; ++e)
    p[e] = (unsigned)f2b(src[2 * e]) | ((unsigned)f2b(src[2 * e + 1]) << 16);
  u4v val = {p[0], p[1], p[2], p[3]};
  *(u4v*)(ws + (size_t)gid * 4) = val;
}

__global__ __launch_bounds__(1024)
__attribute__((amdgpu_waves_per_eu(4, 4)))
void prithvi_fused(
    const float* __restrict__ x,     const float* __restrict__ conv_w,
    const float* __restrict__ bn_g,  const float* __restrict__ bn_b,
    const float* __restrict__ bn_m,  const float* __restrict__ bn_v,
    const float* __restrict__ w_in,  const float* __restrict__ qkv_b,
    const float* __restrict__ ob,    const float* __restrict__ ln1_g,
    const float* __restrict__ ln1_b, const float* __restrict__ ff1_b,
    const float* __restrict__ ff2_b, const float* __restrict__ ln2_g,
    const float* __restrict__ ln2_b, const float* __restrict__ w_out,
    const float* __restrict__ b_out, const float* __restrict__ ws,
    float* __restrict__ out)
{
  // 24576B g2 + 16 x 7296B wave slots + 4352B peL (conv staging aliases slots)
  __shared__ __align__(16) char smem[145664];
  unsigned short* g2 = (unsigned short*)smem;   // [256 sl][12 t][4 c] bf16
  char* twb = smem + 24576;
  float* peL = (float*)(smem + 141312);          // [16 t][stride 68] fp32

  const int sp = blockIdx.x;
  const int tid = threadIdx.x, lane = tid & 63, wave = tid >> 6;

  // ---- pe table: one element per thread (t = tid>>6, d = tid&63) ----
  {
    int t_ = tid >> 6, d_ = tid & 63;
    float freq = expf(-(float)(d_ & ~1) * (9.210340371976184f / 64.f));
    float a = freq * (float)t_;
    peL[t_ * 68 + d_] = (d_ & 1) ? cosf(a) : sinf(a);
  }

  // ---------------- conv: 1 output channel/thread, x staged 4 passes ----
  {
    float* stg = (float*)twb;   // 12288B
    float acc[12];
#pragma unroll
    for (int t = 0; t < 12; ++t) acc[t] = 0.f;
    const int c_ = tid >> 8, jj = tid & 255;
    const int oc = c_ * 256 + jj;
    const float* wrow = conv_w + (size_t)oc * 1024;
#pragma unroll 1
    for (int p = 0; p < 4; ++p) {
      for (int ch2 = tid; ch2 < 3072; ch2 += 1024) {
        int e = ch2 / 12, t = ch2 - 12 * e;
        stg[t * 256 + e] = x[(size_t)((p * 256 + e) * 12 + t) * 256 + sp];
      }
      __syncthreads();
      for (int eb = 0; eb < 256; eb += 4) {
        float4 w4 = *(const float4*)(wrow + p * 256 + eb);
#pragma unroll
        for (int t = 0; t < 12; ++t) {
          float4 xv = *(const float4*)&stg[t * 256 + eb];
          acc[t] = fmaf(xv.x, w4.x, acc[t]);
          acc[t] = fmaf(xv.y, w4.y, acc[t]);
          acc[t] = fmaf(xv.z, w4.z, acc[t]);
          acc[t] = fmaf(xv.w, w4.w, acc[t]);
        }
      }
      __syncthreads();
    }
    float sc = bn_g[oc] * rsqrtf(bn_v[oc] + 1e-5f);
    float sh = fmaf(-bn_m[oc], sc, bn_b[oc]);
#pragma unroll
    for (int t = 0; t < 12; ++t) {
      float z = fmaf(acc[t], sc, sh);
      g2[jj * 48 + t * 4 + c_] = f2b(0.5f * z * (1.f + erff(z * 0.70710678118654752f)));
    }
  }
  __syncthreads();   // g2 + peL read-only; twb free for transformer slots

  // ---------------- phase 3: 1 seq at a time, 16 waves ----------------
  const int ln = lane & 15, grp = lane >> 4;
  char* HB = twb + wave * 7296;
  char* QB = HB + 2432;
  char* KB = HB + 4864;
  const u4v* WS = (const u4v*)ws;
#define BT(T) __builtin_bit_cast(s8v, WS[(T) * 64 + lane])
#define STROW(BUF, ROW, COL, VAL) \
  ((unsigned short*)(BUF))[(ROW) * 76 + (COL)] = (VAL)

  const float bo0 = b_out[0];

#pragma unroll 1
  for (int itr = 0; itr < 16; ++itr) {
    const int sl = wave * 16 + itr;   // seq 0..255
    f4v v[4];

    // ---- h0 (fp32 C-frag) -> HB bf16 ----
    {
      int tb = (grp < 3) ? grp * 4 : 0;
#pragma unroll
      for (int i = 0; i < 4; ++i) {
        uint2 gu = *(const uint2*)(g2 + sl * 48 + (tb + i) * 4);
        float g0 = b2f((unsigned short)(gu.x & 0xffff));
        float g1 = b2f((unsigned short)(gu.x >> 16));
        float g2v = b2f((unsigned short)(gu.y & 0xffff));
        float g3 = b2f((unsigned short)(gu.y >> 16));
#pragma unroll
        for (int j = 0; j < 4; ++j) {
          float4 wi = *(const float4*)(w_in + (j * 16 + ln) * 4);
          float peij = peL[(grp * 4 + i) * 68 + j * 16 + ln];
          v[j][i] = fmaf(g0, wi.x, fmaf(g1, wi.y,
                    fmaf(g2v, wi.z, fmaf(g3, wi.w, peij))));
        }
      }
#pragma unroll
      for (int i = 0; i < 4; ++i)
#pragma unroll
        for (int j = 0; j < 4; ++j)
          STROW(HB, grp * 4 + i, j * 16 + ln, f2b(v[j][i]));
    }

#pragma unroll 1
    for (int l = 0; l < 2; ++l) {
      s4v vfrag[4];
      // ---- QKV: Q -> QB, K -> KB, V -> regs (C-frag == PV B-frag) ----
      {
        s8v a0 = *(const s8v*)(HB + ln * 152 + grp * 16);
        s8v a1 = *(const s8v*)(HB + ln * 152 + 64 + grp * 16);
#pragma unroll
        for (int j = 0; j < 12; ++j) {
          float bb = qkv_b[l * 192 + j * 16 + ln];
          f4v c = {bb, bb, bb, bb};
          c = MFMA32(a0, BT(l * 24 + j), c);
          c = MFMA32(a1, BT(l * 24 + 12 + j), c);
          if (j < 4) {
#pragma unroll
            for (int i = 0; i < 4; ++i)
              STROW(QB, grp * 4 + i, j * 16 + ln, f2b(c[i]));
          } else if (j < 8) {
#pragma unroll
            for (int i = 0; i < 4; ++i)
              STROW(KB, grp * 4 + i, (j - 4) * 16 + ln, f2b(c[i]));
          } else {
            s4v pv;
            pv[0] = (short)f2b(c[0]); pv[1] = (short)f2b(c[1]);
            pv[2] = (short)f2b(c[2]); pv[3] = (short)f2b(c[3]);
            vfrag[j - 8] = pv;
          }
        }
      }
      // ---- attention: S^T = mfma(K,Q); O -> KB (K dead per head) ----
      {
        const f4v z4 = {0.f, 0.f, 0.f, 0.f};
#pragma unroll
        for (int hh = 0; hh < 4; ++hh) {
          s4v aK = *(const s4v*)(KB + ln * 152 + hh * 32 + grp * 8);
          s4v bQ = *(const s4v*)(QB + ln * 152 + hh * 32 + grp * 8);
          f4v sc = MFMA16(aK, bQ, z4);   // lane: score(q=ln, k=grp*4+i)
          float e0, e1, e2, e3;
          if (grp == 3) { e0 = e1 = e2 = e3 = 0.f; }
          else {
            e0 = __expf(sc[0] * 0.25f); e1 = __expf(sc[1] * 0.25f);
            e2 = __expf(sc[2] * 0.25f); e3 = __expf(sc[3] * 0.25f);
          }
          float sm = (e0 + e1) + (e2 + e3);
          sm += __shfl_xor(sm, 16);
          sm += __shfl_xor(sm, 32);
          float inv = __builtin_amdgcn_rcpf(sm);
          s4v aP;
          aP[0] = (short)f2b(e0 * inv); aP[1] = (short)f2b(e1 * inv);
          aP[2] = (short)f2b(e2 * inv); aP[3] = (short)f2b(e3 * inv);
          f4v o4 = MFMA16(aP, vfrag[hh], z4);
#pragma unroll
          for (int i = 0; i < 4; ++i)
            STROW(KB, grp * 4 + i, hh * 16 + ln, f2b(o4[i]));
        }
      }
      // ---- O-proj (O in KB) + bias folded into residual v ----
      {
        s8v a0 = *(const s8v*)(KB + ln * 152 + grp * 16);
        s8v a1 = *(const s8v*)(KB + ln * 152 + 64 + grp * 16);
#pragma unroll
        for (int j = 0; j < 4; ++j) {
          float bb = ob[l * 64 + j * 16 + ln];
          f4v bb4 = {bb, bb, bb, bb};
          v[j] += bb4;
          v[j] = MFMA32(a0, BT(48 + l * 8 + j), v[j]);
          v[j] = MFMA32(a1, BT(48 + l * 8 + 4 + j), v[j]);
        }
      }
      // ---- LN1 -> HB ----
      {
        const float* gp = ln1_g + l * 64;
        const float* bp = ln1_b + l * 64;
#pragma unroll
        for (int i = 0; i < 4; ++i) {
          float sm = v[0][i] + v[1][i] + v[2][i] + v[3][i];
          sm += __shfl_xor(sm, 1); sm += __shfl_xor(sm, 2);
          sm += __shfl_xor(sm, 4); sm += __shfl_xor(sm, 8);
          float mean = sm * 0.015625f;
          float q = 0.f;
#pragma unroll
          for (int j = 0; j < 4; ++j) { float d = v[j][i] - mean; q = fmaf(d, d, q); }
          q += __shfl_xor(q, 1); q += __shfl_xor(q, 2);
          q += __shfl_xor(q, 4); q += __shfl_xor(q, 8);
          float rs = rsqrtf(q * 0.015625f + 1e-5f);
#pragma unroll
          for (int j = 0; j < 4; ++j) {
            float nv = fmaf((v[j][i] - mean) * rs, gp[j * 16 + ln], bp[j * 16 + ln]);
            v[j][i] = nv;
            STROW(HB, grp * 4 + i, j * 16 + ln, f2b(nv));
          }
        }
      }
      // ---- FF: 2 halves of 128 ff-dims through F (aliases QB+KB, stride 140) ----
      {
        s8v ha0 = *(const s8v*)(HB + ln * 152 + grp * 16);
        s8v ha1 = *(const s8v*)(HB + ln * 152 + 64 + grp * 16);
#pragma unroll
        for (int j = 0; j < 4; ++j) {
          float bb = ff2_b[l * 64 + j * 16 + ln];
          f4v bb4 = {bb, bb, bb, bb};
          v[j] += bb4;
        }
#pragma unroll
        for (int fh = 0; fh < 2; ++fh) {
#pragma unroll
          for (int j8 = 0; j8 < 8; ++j8) {
            int jt = fh * 8 + j8;
            float bb = ff1_b[l * 256 + jt * 16 + ln];
            f4v c = {bb, bb, bb, bb};
            c = MFMA32(ha0, BT(64 + l * 32 + jt), c);
            c = MFMA32(ha1, BT(64 + l * 32 + 16 + jt), c);
#pragma unroll
            for (int i = 0; i < 4; ++i)
              ((unsigned short*)QB)[(grp * 4 + i) * 140 + j8 * 16 + ln] =
                  f2b(fmaxf(c[i], 0.f));
          }
#pragma unroll
          for (int kk2 = 0; kk2 < 4; ++kk2) {
            int kkg = fh * 4 + kk2;
            s8v fa = *(const s8v*)(QB + ln * 280 + kk2 * 64 + grp * 16);
            v[0] = MFMA32(fa, BT(128 + l * 32 + kkg * 4 + 0), v[0]);
            v[1] = MFMA32(fa, BT(128 + l * 32 + kkg * 4 + 1), v[1]);
            v[2] = MFMA32(fa, BT(128 + l * 32 + kkg * 4 + 2), v[2]);
            v[3] = MFMA32(fa, BT(128 + l * 32 + kkg * 4 + 3), v[3]);
          }
        }
      }
      // ---- LN2 (store to HB only if another layer follows) ----
      {
        const float* gp = ln2_g + l * 64;
        const float* bp = ln2_b + l * 64;
#pragma unroll
        for (int i = 0; i < 4; ++i) {
          float sm = v[0][i] + v[1][i] + v[2][i] + v[3][i];
          sm += __shfl_xor(sm, 1); sm += __shfl_xor(sm, 2);
          sm += __shfl_xor(sm, 4); sm += __shfl_xor(sm, 8);
          float mean = sm * 0.015625f;
          float q = 0.f;
#pragma unroll
          for (int j = 0; j < 4; ++j) { float d = v[j][i] - mean; q = fmaf(d, d, q); }
          q += __shfl_xor(q, 1); q += __shfl_xor(q, 2);
          q += __shfl_xor(q, 4); q += __shfl_xor(q, 8);
          float rs = rsqrtf(q * 0.015625f + 1e-5f);
#pragma unroll
          for (int j = 0; j < 4; ++j) {
            float nv = fmaf((v[j][i] - mean) * rs, gp[j * 16 + ln], bp[j * 16 + ln]);
            v[j][i] = nv;
            if (l == 0) STROW(HB, grp * 4 + i, j * 16 + ln, f2b(nv));
          }
        }
      }
    } // layer

    // ---- head: mean over t, dot w_out, sigmoid ----
    {
      float dp = 0.f;
#pragma unroll
      for (int j = 0; j < 4; ++j) {
        float c0 = (grp < 3) ? (v[j][0] + v[j][1] + v[j][2] + v[j][3]) : 0.f;
        c0 += __shfl_xor(c0, 16);
        c0 += __shfl_xor(c0, 32);
        dp = fmaf(c0, w_out[j * 16 + ln], dp);
      }
      dp += __shfl_xor(dp, 1);
      dp += __shfl_xor(dp, 2);
      dp += __shfl_xor(dp, 4);
      dp += __shfl_xor(dp, 8);
      if (lane == 0) {
        float logit = dp * (1.f / 12.f) + bo0;
        int hf = ((sp >> 4) << 4) | (sl >> 4);
        int wf = ((sp & 15) << 4) | (sl & 15);
        out[hf * 256 + wf] = 1.f / (1.f + expf(-logit));
      }
    }
  } // seq loop
#undef BT
#undef STROW
}

extern "C" void kernel_launch(void* const* d_in, const int* in_sizes, int n_in,
                              void* d_out, int out_size, void* d_ws, size_t ws_size,
                              hipStream_t stream) {
  (void)in_sizes; (void)n_in; (void)out_size; (void)ws_size;
  wpack<<<48, 256, 0, stream>>>(
      (const float*)d_in[7],  (const float*)d_in[9],
      (const float*)d_in[13], (const float*)d_in[15], (unsigned int*)d_ws);
  prithvi_fused<<<256, 1024, 0, stream>>>(
      (const float*)d_in[0],  (const float*)d_in[1],  (const float*)d_in[2],
      (const float*)d_in[3],  (const float*)d_in[4],  (const float*)d_in[5],
      (const float*)d_in[6],  (const float*)d_in[8],  (const float*)d_in[10],
      (const float*)d_in[11], (const float*)d_in[12], (const float*)d_in[14],
      (const float*)d_in[16], (const float*)d_in[17], (const float*)d_in[18],
      (const float*)d_in[19], (const float*)d_in[20], (const float*)d_ws,
      (float*)d_out);
}

// Round 17
// 749.560 us; speedup vs baseline: 1.0287x; 1.0287x over previous
//
#include <hip/hip_runtime.h>
#include <math.h>

// R16 = R15 + register-resident attention via operand-role algebra:
//  - h-frag s8v serves as A (h) AND B (h^T) for MFMA32 (same register!).
//  - Q^T,K^T = mfma32(A=WqA-pack, B=h-frag): C-frag(Q^T) == scores B-operand;
//    C-frag(K^T) == scores A-operand (C-frag-as-A = transpose).
//  - V C-frag == PV B-frag (as before); O^T = mfma16(A=V, B=P);
//    O^T-frag-as-A feeds O-proj as 16 mfma16 w/ Wo^T pack.
//  => Q/K/O never touch LDS; per-head fusion keeps 3 s4v live per head.
//  FF + LN unchanged (MFMA32; F through LDS). DS ops in seq loop -55%.

typedef __attribute__((ext_vector_type(8))) short s8v;
typedef __attribute__((ext_vector_type(4))) short s4v;
typedef __attribute__((ext_vector_type(4))) float f4v;
typedef __attribute__((ext_vector_type(4))) unsigned int u4v;

#define MFMA32(A, B, C) __builtin_amdgcn_mfma_f32_16x16x32_bf16((A), (B), (C), 0, 0, 0)
#define MFMA16(A, B, C) __builtin_amdgcn_mfma_f32_16x16x16bf16_1k((A), (B), (C), 0, 0, 0)

static __device__ __forceinline__ unsigned short f2b(float f) {
  return __builtin_bit_cast(unsigned short, (__bf16)f);
}
static __device__ __forceinline__ float b2f(unsigned short h) {
  return __builtin_bit_cast(float, ((unsigned)h) << 16);
}
static __device__ __forceinline__ s4v c4(f4v v) {
  s4v r;
  r[0] = (short)f2b(v[0]); r[1] = (short)f2b(v[1]);
  r[2] = (short)f2b(v[2]); r[3] = (short)f2b(v[3]);
  return r;
}

// ---- prologue: pack weights (bf16) ----
// B-pack tiles (MFMA32 B-op), 1024B each, T=0..191: lane holds
//   B[k=kk*32+(l>>4)*8+e][n=j*16+(l&15)], e=0..7
//   qkv T=l*24+kk*12+j | ow 48+l*8+kk*4+j | ff1 64+l*32+kk*16+j | ff2 128+l*32+kkg*4+j
// A-pack tiles (MFMA32 A-op) T=192..223: lane holds W[m=jo*16+(l&15)][k=kk*32+(l>>4)*8+e]
//   T = 192 + l*16 + mat*8 + jo*2 + kk  (mat 0=Q,1=K)
// WoT16 packs (MFMA16 B-op), 512B each at byte 229376: E = l*16 + hh*4 + jo:
//   lane holds Wo[jo*16+(l&15)][hh*16+(l>>4)*4+e], e=0..3
__global__ __launch_bounds__(256) void wpack(
    const float* __restrict__ qkv_w, const float* __restrict__ ow,
    const float* __restrict__ ff1_w, const float* __restrict__ ff2_w,
    unsigned int* __restrict__ ws) {
  int gid = blockIdx.x * 256 + threadIdx.x;   // 0..16383
  int tIdx = gid >> 6, lane = gid & 63;
  int ln = lane & 15, grp = lane >> 4;
  if (tIdx < 224) {
    const float* src;
    if (tIdx < 48) {
      int l = tIdx / 24, r = tIdx % 24, kk = r / 12, j = r % 12;
      src = qkv_w + l * 12288 + (j * 16 + ln) * 64 + kk * 32 + grp * 8;
    } else if (tIdx < 64) {
      int u = tIdx - 48, l = u / 8, r = u % 8, kk = r / 4, j = r % 4;
      src = ow + l * 4096 + (j * 16 + ln) * 64 + kk * 32 + grp * 8;
    } else if (tIdx < 128) {
      int u = tIdx - 64, l = u / 32, r = u % 32, kk = r / 16, j = r % 16;
      src = ff1_w + l * 16384 + (j * 16 + ln) * 64 + kk * 32 + grp * 8;
    } else if (tIdx < 192) {
      int u = tIdx - 128, l = u / 32, r = u % 32, kk = r / 4, j = r % 4;
      src = ff2_w + l * 16384 + (j * 16 + ln) * 256 + kk * 32 + grp * 8;
    } else {
      int u = tIdx - 192, l = u / 16, r = u % 16, mat = r / 8, q = r % 8, jo = q / 2, kk = q % 2;
      src = qkv_w + l * 12288 + mat * 4096 + (jo * 16 + ln) * 64 + kk * 32 + grp * 8;
    }
    unsigned p[4];
#pragma unroll
    for (int e = 0; e < 4; ++e)
      p[e] = (unsigned)f2b(src[2 * e]) | ((unsigned)f2b(src[2 * e + 1]) << 16);
    u4v val = {p[0], p[1], p[2], p[3]};
    *(u4v*)(ws + (size_t)gid * 4) = val;
  } else if (tIdx < 256) {
    int E = tIdx - 224, l = E / 16, r = E % 16, hh = r / 4, jo = r % 4;
    const float* src = ow + l * 4096 + (jo * 16 + ln) * 64 + hh * 16 + grp * 4;
    unsigned lo = (unsigned)f2b(src[0]) | ((unsigned)f2b(src[1]) << 16);
    unsigned hi = (unsigned)f2b(src[2]) | ((unsigned)f2b(src[3]) << 16);
    *(uint2*)((char*)ws + 229376 + E * 512 + lane * 8) = make_uint2(lo, hi);
  }
}

__global__ __launch_bounds__(1024) void prithvi_fused(
    const float* __restrict__ x,     const float* __restrict__ conv_w,
    const float* __restrict__ bn_g,  const float* __restrict__ bn_b,
    const float* __restrict__ bn_m,  const float* __restrict__ bn_v,
    const float* __restrict__ w_in,  const float* __restrict__ qkv_b,
    const float* __restrict__ ob,    const float* __restrict__ ln1_g,
    const float* __restrict__ ln1_b, const float* __restrict__ ff1_b,
    const float* __restrict__ ff2_b, const float* __restrict__ ln2_g,
    const float* __restrict__ ln2_b, const float* __restrict__ w_out,
    const float* __restrict__ b_out, const float* __restrict__ ws,
    float* __restrict__ out)
{
  // 24576B g2 + 16 x 6912B slots (HB 2432 | F 4480) + 4352B peL
  __shared__ __align__(16) char smem[139520];
  unsigned short* g2 = (unsigned short*)smem;   // [256 sl][12 t][4 c] bf16
  char* twb = smem + 24576;
  float* peL = (float*)(smem + 135168);          // [16 t][stride 68] fp32

  const int sp = blockIdx.x;
  const int tid = threadIdx.x, lane = tid & 63, wave = tid >> 6;

  // ---- pe table: one element per thread (t = tid>>6, d = tid&63) ----
  {
    int t_ = tid >> 6, d_ = tid & 63;
    float freq = expf(-(float)(d_ & ~1) * (9.210340371976184f / 64.f));
    float a = freq * (float)t_;
    peL[t_ * 68 + d_] = (d_ & 1) ? cosf(a) : sinf(a);
  }

  // ---------------- conv: 1 output channel/thread, x staged 4 passes ----
  {
    float* stg = (float*)twb;   // 12288B
    float acc[12];
#pragma unroll
    for (int t = 0; t < 12; ++t) acc[t] = 0.f;
    const int c_ = tid >> 8, jj = tid & 255;
    const int oc = c_ * 256 + jj;
    const float* wrow = conv_w + (size_t)oc * 1024;
#pragma unroll 1
    for (int p = 0; p < 4; ++p) {
      for (int ch2 = tid; ch2 < 3072; ch2 += 1024) {
        int e = ch2 / 12, t = ch2 - 12 * e;
        stg[t * 256 + e] = x[(size_t)((p * 256 + e) * 12 + t) * 256 + sp];
      }
      __syncthreads();
      for (int eb = 0; eb < 256; eb += 4) {
        float4 w4 = *(const float4*)(wrow + p * 256 + eb);
#pragma unroll
        for (int t = 0; t < 12; ++t) {
          float4 xv = *(const float4*)&stg[t * 256 + eb];
          acc[t] = fmaf(xv.x, w4.x, acc[t]);
          acc[t] = fmaf(xv.y, w4.y, acc[t]);
          acc[t] = fmaf(xv.z, w4.z, acc[t]);
          acc[t] = fmaf(xv.w, w4.w, acc[t]);
        }
      }
      __syncthreads();
    }
    float sc = bn_g[oc] * rsqrtf(bn_v[oc] + 1e-5f);
    float sh = fmaf(-bn_m[oc], sc, bn_b[oc]);
#pragma unroll
    for (int t = 0; t < 12; ++t) {
      float z = fmaf(acc[t], sc, sh);
      g2[jj * 48 + t * 4 + c_] = f2b(0.5f * z * (1.f + erff(z * 0.70710678118654752f)));
    }
  }
  __syncthreads();   // g2 + peL read-only; twb free for transformer slots

  // ---------------- phase 3: 1 seq at a time, 16 waves ----------------
  const int ln = lane & 15, grp = lane >> 4;
  char* HB = twb + wave * 6912;
  char* FB = HB + 2432;                 // [16 rows][140 ush]
  const u4v* WS = (const u4v*)ws;
#define BT(T) __builtin_bit_cast(s8v, WS[(T) * 64 + lane])
#define WO16(E) __builtin_bit_cast(s4v, *(const uint2*)((const char*)ws + 229376 + (E) * 512 + lane * 8))
#define STROW(BUF, ROW, COL, VAL) \
  ((unsigned short*)(BUF))[(ROW) * 76 + (COL)] = (VAL)

  const float bo0 = b_out[0];

#pragma unroll 1
  for (int itr = 0; itr < 16; ++itr) {
    const int sl = wave * 16 + itr;   // seq 0..255
    f4v v[4];

    // ---- h0 (fp32 C-frag) -> HB bf16 ----
    {
      int tb = (grp < 3) ? grp * 4 : 0;
#pragma unroll
      for (int i = 0; i < 4; ++i) {
        uint2 gu = *(const uint2*)(g2 + sl * 48 + (tb + i) * 4);
        float g0 = b2f((unsigned short)(gu.x & 0xffff));
        float g1 = b2f((unsigned short)(gu.x >> 16));
        float g2v = b2f((unsigned short)(gu.y & 0xffff));
        float g3 = b2f((unsigned short)(gu.y >> 16));
#pragma unroll
        for (int j = 0; j < 4; ++j) {
          float4 wi = *(const float4*)(w_in + (j * 16 + ln) * 4);
          float peij = peL[(grp * 4 + i) * 68 + j * 16 + ln];
          v[j][i] = fmaf(g0, wi.x, fmaf(g1, wi.y,
                    fmaf(g2v, wi.z, fmaf(g3, wi.w, peij))));
        }
      }
#pragma unroll
      for (int i = 0; i < 4; ++i)
#pragma unroll
        for (int j = 0; j < 4; ++j)
          STROW(HB, grp * 4 + i, j * 16 + ln, f2b(v[j][i]));
    }

#pragma unroll 1
    for (int l = 0; l < 2; ++l) {
      const f4v z4 = {0.f, 0.f, 0.f, 0.f};
      s4v Ot[4];
      // ---- fused per-head QKV + attention, all in registers ----
      {
        s8v a0 = *(const s8v*)(HB + ln * 152 + grp * 16);
        s8v a1 = *(const s8v*)(HB + ln * 152 + 64 + grp * 16);
#pragma unroll
        for (int hh = 0; hh < 4; ++hh) {
          // Q^T, K^T: A = weight A-pack, B = h-frag (same register as A use)
          float4 bq = *(const float4*)(qkv_b + l * 192 + hh * 16 + grp * 4);
          f4v cq = {bq.x, bq.y, bq.z, bq.w};
          cq = MFMA32(BT(192 + l * 16 + hh * 2 + 0), a0, cq);
          cq = MFMA32(BT(192 + l * 16 + hh * 2 + 1), a1, cq);
          float4 bk = *(const float4*)(qkv_b + l * 192 + 64 + hh * 16 + grp * 4);
          f4v ck = {bk.x, bk.y, bk.z, bk.w};
          ck = MFMA32(BT(192 + l * 16 + 8 + hh * 2 + 0), a0, ck);
          ck = MFMA32(BT(192 + l * 16 + 8 + hh * 2 + 1), a1, ck);
          // V (normal orientation): A = h-frag, B = B-pack
          float bb = qkv_b[l * 192 + 128 + hh * 16 + ln];
          f4v cv = {bb, bb, bb, bb};
          cv = MFMA32(a0, BT(l * 24 + 8 + hh), cv);
          cv = MFMA32(a1, BT(l * 24 + 20 + hh), cv);
          s4v q4 = c4(cq), k4 = c4(ck), v4 = c4(cv);
          // scores: S^T = K . Q^T (A = K^T-frag-as-A, B = Q^T-frag)
          f4v sc = MFMA16(k4, q4, z4);   // lane: score(q=ln, k=grp*4+i)
          float e0, e1, e2, e3;
          if (grp == 3) { e0 = e1 = e2 = e3 = 0.f; }
          else {
            e0 = __expf(sc[0] * 0.25f); e1 = __expf(sc[1] * 0.25f);
            e2 = __expf(sc[2] * 0.25f); e3 = __expf(sc[3] * 0.25f);
          }
          float sm = (e0 + e1) + (e2 + e3);
          sm += __shfl_xor(sm, 16);
          sm += __shfl_xor(sm, 32);
          float inv = __builtin_amdgcn_rcpf(sm);
          s4v aP;
          aP[0] = (short)f2b(e0 * inv); aP[1] = (short)f2b(e1 * inv);
          aP[2] = (short)f2b(e2 * inv); aP[3] = (short)f2b(e3 * inv);
          // O^T = V^T . P^T (A = V-frag-as-A, B = P-frag)
          Ot[hh] = c4(MFMA16(v4, aP, z4));
        }
      }
      // ---- O-proj: v += O . Wo^T via 16 mfma16 (A = O^T-frag-as-A) ----
      {
#pragma unroll
        for (int jo = 0; jo < 4; ++jo) {
          float bb = ob[l * 64 + jo * 16 + ln];
          f4v bb4 = {bb, bb, bb, bb};
          v[jo] += bb4;
        }
#pragma unroll
        for (int hh = 0; hh < 4; ++hh)
#pragma unroll
          for (int jo = 0; jo < 4; ++jo)
            v[jo] = MFMA16(Ot[hh], WO16(l * 16 + hh * 4 + jo), v[jo]);
      }
      // ---- LN1 -> HB ----
      {
        const float* gp = ln1_g + l * 64;
        const float* bp = ln1_b + l * 64;
#pragma unroll
        for (int i = 0; i < 4; ++i) {
          float sm = v[0][i] + v[1][i] + v[2][i] + v[3][i];
          sm += __shfl_xor(sm, 1); sm += __shfl_xor(sm, 2);
          sm += __shfl_xor(sm, 4); sm += __shfl_xor(sm, 8);
          float mean = sm * 0.015625f;
          float q = 0.f;
#pragma unroll
          for (int j = 0; j < 4; ++j) { float d = v[j][i] - mean; q = fmaf(d, d, q); }
          q += __shfl_xor(q, 1); q += __shfl_xor(q, 2);
          q += __shfl_xor(q, 4); q += __shfl_xor(q, 8);
          float rs = rsqrtf(q * 0.015625f + 1e-5f);
#pragma unroll
          for (int j = 0; j < 4; ++j) {
            float nv = fmaf((v[j][i] - mean) * rs, gp[j * 16 + ln], bp[j * 16 + ln]);
            v[j][i] = nv;
            STROW(HB, grp * 4 + i, j * 16 + ln, f2b(nv));
          }
        }
      }
      // ---- FF: 2 halves of 128 ff-dims through FB (stride 140) ----
      {
        s8v ha0 = *(const s8v*)(HB + ln * 152 + grp * 16);
        s8v ha1 = *(const s8v*)(HB + ln * 152 + 64 + grp * 16);
#pragma unroll
        for (int j = 0; j < 4; ++j) {
          float bb = ff2_b[l * 64 + j * 16 + ln];
          f4v bb4 = {bb, bb, bb, bb};
          v[j] += bb4;
        }
#pragma unroll
        for (int fh = 0; fh < 2; ++fh) {
#pragma unroll
          for (int j8 = 0; j8 < 8; ++j8) {
            int jt = fh * 8 + j8;
            float bb = ff1_b[l * 256 + jt * 16 + ln];
            f4v c = {bb, bb, bb, bb};
            c = MFMA32(ha0, BT(64 + l * 32 + jt), c);
            c = MFMA32(ha1, BT(64 + l * 32 + 16 + jt), c);
#pragma unroll
            for (int i = 0; i < 4; ++i)
              ((unsigned short*)FB)[(grp * 4 + i) * 140 + j8 * 16 + ln] =
                  f2b(fmaxf(c[i], 0.f));
          }
#pragma unroll
          for (int kk2 = 0; kk2 < 4; ++kk2) {
            int kkg = fh * 4 + kk2;
            s8v fa = *(const s8v*)(FB + ln * 280 + kk2 * 64 + grp * 16);
            v[0] = MFMA32(fa, BT(128 + l * 32 + kkg * 4 + 0), v[0]);
            v[1] = MFMA32(fa, BT(128 + l * 32 + kkg * 4 + 1), v[1]);
            v[2] = MFMA32(fa, BT(128 + l * 32 + kkg * 4 + 2), v[2]);
            v[3] = MFMA32(fa, BT(128 + l * 32 + kkg * 4 + 3), v[3]);
          }
        }
      }
      // ---- LN2 (store to HB only if another layer follows) ----
      {
        const float* gp = ln2_g + l * 64;
        const float* bp = ln2_b + l * 64;
#pragma unroll
        for (int i = 0; i < 4; ++i) {
          float sm = v[0][i] + v[1][i] + v[2][i] + v[3][i];
          sm += __shfl_xor(sm, 1); sm += __shfl_xor(sm, 2);
          sm += __shfl_xor(sm, 4); sm += __shfl_xor(sm, 8);
          float mean = sm * 0.015625f;
          float q = 0.f;
#pragma unroll
          for (int j = 0; j < 4; ++j) { float d = v[j][i] - mean; q = fmaf(d, d, q); }
          q += __shfl_xor(q, 1); q += __shfl_xor(q, 2);
          q += __shfl_xor(q, 4); q += __shfl_xor(q, 8);
          float rs = rsqrtf(q * 0.015625f + 1e-5f);
#pragma unroll
          for (int j = 0; j < 4; ++j) {
            float nv = fmaf((v[j][i] - mean) * rs, gp[j * 16 + ln], bp[j * 16 + ln]);
            v[j][i] = nv;
            if (l == 0) STROW(HB, grp * 4 + i, j * 16 + ln, f2b(nv));
          }
        }
      }
    } // layer

    // ---- head: mean over t, dot w_out, sigmoid ----
    {
      float dp = 0.f;
#pragma unroll
      for (int j = 0; j < 4; ++j) {
        float c0 = (grp < 3) ? (v[j][0] + v[j][1] + v[j][2] + v[j][3]) : 0.f;
        c0 += __shfl_xor(c0, 16);
        c0 += __shfl_xor(c0, 32);
        dp = fmaf(c0, w_out[j * 16 + ln], dp);
      }
      dp += __shfl_xor(dp, 1);
      dp += __shfl_xor(dp, 2);
      dp += __shfl_xor(dp, 4);
      dp += __shfl_xor(dp, 8);
      if (lane == 0) {
        float logit = dp * (1.f / 12.f) + bo0;
        int hf = ((sp >> 4) << 4) | (sl >> 4);
        int wf = ((sp & 15) << 4) | (sl & 15);
        out[hf * 256 + wf] = 1.f / (1.f + expf(-logit));
      }
    }
  } // seq loop
#undef BT
#undef WO16
#undef STROW
}

extern "C" void kernel_launch(void* const* d_in, const int* in_sizes, int n_in,
                              void* d_out, int out_size, void* d_ws, size_t ws_size,
                              hipStream_t stream) {
  (void)in_sizes; (void)n_in; (void)out_size; (void)ws_size;
  wpack<<<64, 256, 0, stream>>>(
      (const float*)d_in[7],  (const float*)d_in[9],
      (const float*)d_in[13], (const float*)d_in[15], (unsigned int*)d_ws);
  prithvi_fused<<<256, 1024, 0, stream>>>(
      (const float*)d_in[0],  (const float*)d_in[1],  (const float*)d_in[2],
      (const float*)d_in[3],  (const float*)d_in[4],  (const float*)d_in[5],
      (const float*)d_in[6],  (const float*)d_in[8],  (const float*)d_in[10],
      (const float*)d_in[11], (const float*)d_in[12], (const float*)d_in[14],
      (const float*)d_in[16], (const float*)d_in[17], (const float*)d_in[18],
      (const float*)d_in[19], (const float*)d_in[20], (const float*)d_ws,
      (float*)d_out);
}